// Round 8
// baseline (24.879 us; speedup 1.0000x reference)
//
#include <hip/hip_runtime.h>
#include <math.h>
#include <stdint.h>

// ---------------------------------------------------------------------------
// VNFrameEstimator, fully-f32 single fused kernel (R7 structure, VALU-trimmed):
//  - 16 lanes/batch, per-lane contiguous 96B (6x float4) loads; TWO batches
//    in flight per lane (12 dwordx4) before any use.
//  - normalize with raw v_rsq_f32 on fmaxf-guarded n2 (bit-identical to the
//    reference's 1e-12 clamp for the degenerate case).
//  - 8 moments only: zz recovered via trace identity (sum of unit norms = C).
//  - 16-lane DPP row_ror rotate-reduce (4 steps x 8 moments).
//  - fused tail: 1 thread/batch f32 3x3 Jacobi, 4 sweeps (12 rotations),
//    sort, sign-fix, cross; frames staged in LDS, coalesced dwordx4 stores.
// ---------------------------------------------------------------------------

#define BLOCK 256
#define BPB   32   // 4 waves * 4 groups * 2 batches-per-group

// f32 rotate within the 16-lane DPP row (pure VALU). CTRL: ROW_ROR:N = 0x120|N.
template <int CTRL>
__device__ __forceinline__ float ror16_f32(float v) {
    union { float f; int i; } u, r;
    u.f = v;
    r.i = __builtin_amdgcn_mov_dpp(u.i, CTRL, 0xF, 0xF, true);
    return r.f;
}

// f32 1/sqrt, ~1 ulp (HW seed + 1 NR)
__device__ __forceinline__ float frsqrt(float x) {
    float r = __builtin_amdgcn_rsqf(x);
    return r * fmaf(-0.5f * x, r * r, 1.5f);
}
// f32 1/x, ~1 ulp (HW seed + 1 NR)
__device__ __forceinline__ float frcp(float x) {
    float r = __builtin_amdgcn_rcpf(x);
    return r * fmaf(-x, r, 2.0f);
}

// One f32 Jacobi rotation zeroing A[P][Q]; R is the remaining index.
template <int P, int Q, int R>
__device__ __forceinline__ void jrot(float (&A)[3][3], float (&V)[3][3]) {
    float apq = A[P][Q];
    if (fabsf(apq) > 1e-12f) {
        float theta = (A[Q][Q] - A[P][P]) * 0.5f * frcp(apq);
        float q = fmaf(theta, theta, 1.0f);
        float sq = q * frsqrt(q);                  // sqrt(theta^2+1)
        float t = frcp(fabsf(theta) + sq);
        if (theta < 0.0f) t = -t;
        float c = frsqrt(fmaf(t, t, 1.0f));
        float s = t * c;
        float apq_t = t * apq;
        A[P][P] = A[P][P] - apq_t;
        A[Q][Q] = A[Q][Q] + apq_t;
        A[P][Q] = 0.0f;
        A[Q][P] = 0.0f;
        float apr = A[P][R], aqr = A[Q][R];
        A[P][R] = fmaf(c, apr, -s * aqr); A[R][P] = A[P][R];
        A[Q][R] = fmaf(s, apr,  c * aqr); A[R][Q] = A[Q][R];
#pragma unroll
        for (int i = 0; i < 3; ++i) {
            float vip = V[i][P], viq = V[i][Q];
            V[i][P] = fmaf(c, vip, -s * viq);
            V[i][Q] = fmaf(s, vip,  c * viq);
        }
    }
}

// accumulate 8 vectors (24 floats) into 8 f32 moments
// m: [0]=xx [1]=xy [2]=xz [3]=yy [4]=yz [5]=sx [6]=sy [7]=sz   (zz via trace)
__device__ __forceinline__ void accum8(const float4 (&q)[6], float (&m)[8]) {
    float f[24];
#pragma unroll
    for (int i = 0; i < 6; ++i) {
        f[4 * i + 0] = q[i].x; f[4 * i + 1] = q[i].y;
        f[4 * i + 2] = q[i].z; f[4 * i + 3] = q[i].w;
    }
#pragma unroll
    for (int k = 0; k < 8; ++k) {
        float fx = f[3 * k + 0];
        float fy = f[3 * k + 1];
        float fz = f[3 * k + 2];
        float n2 = fmaf(fx, fx, fmaf(fy, fy, fz * fz));
        // rsq(max(n2,1e-24)) == old branch exactly (rsq(1e-24)=1e12)
        float inv = __builtin_amdgcn_rsqf(fmaxf(n2, 1e-24f));
        float x = fx * inv;
        float y = fy * inv;
        float z = fz * inv;
        m[0] = fmaf(x, x, m[0]);
        m[1] = fmaf(x, y, m[1]);
        m[2] = fmaf(x, z, m[2]);
        m[3] = fmaf(y, y, m[3]);
        m[4] = fmaf(y, z, m[4]);
        m[5] += x; m[6] += y; m[7] += z;
    }
}

__device__ __forceinline__ void reduce16(float (&m)[8]) {
#pragma unroll
    for (int k = 0; k < 8; ++k) m[k] += ror16_f32<0x121>(m[k]);
#pragma unroll
    for (int k = 0; k < 8; ++k) m[k] += ror16_f32<0x122>(m[k]);
#pragma unroll
    for (int k = 0; k < 8; ++k) m[k] += ror16_f32<0x124>(m[k]);
#pragma unroll
    for (int k = 0; k < 8; ++k) m[k] += ror16_f32<0x128>(m[k]);
}

__global__ __launch_bounds__(BLOCK) void vn_fused(
    const float* __restrict__ vf, float* __restrict__ out, int B) {
    __shared__ __align__(16) float sA[BPB][9];   // moments, then frames

    const int tid  = threadIdx.x;
    const int wave = tid >> 6;
    const int lane = tid & 63;
    const int g    = lane >> 4;   // group within wave
    const int sub  = lane & 15;   // lane within 16-group

    const int blockBase = blockIdx.x * BPB;
    const int slotA = wave * 8 + g;       // batches 0..3 of this wave's 8
    const int slotB = wave * 8 + 4 + g;   // batches 4..7
    const int bA = blockBase + slotA;
    const int bB = blockBase + slotB;

    // issue ALL loads (12 dwordx4/lane) before any use
    float4 qa[6], qb[6];
    if (bA < B) {
        const float4* pa =
            reinterpret_cast<const float4*>(vf + (size_t)bA * 384 + sub * 24);
#pragma unroll
        for (int i = 0; i < 6; ++i) qa[i] = pa[i];
    }
    if (bB < B) {
        const float4* pb =
            reinterpret_cast<const float4*>(vf + (size_t)bB * 384 + sub * 24);
#pragma unroll
        for (int i = 0; i < 6; ++i) qb[i] = pb[i];
    }

    if (bA < B) {
        float m[8];
#pragma unroll
        for (int k = 0; k < 8; ++k) m[k] = 0.0f;
        accum8(qa, m);
        reduce16(m);
        if (sub == 0) {
#pragma unroll
            for (int k = 0; k < 8; ++k) sA[slotA][k] = m[k];
        }
    }
    if (bB < B) {
        float m[8];
#pragma unroll
        for (int k = 0; k < 8; ++k) m[k] = 0.0f;
        accum8(qb, m);
        reduce16(m);
        if (sub == 0) {
#pragma unroll
            for (int k = 0; k < 8; ++k) sA[slotB][k] = m[k];
        }
    }

    __syncthreads();

    // ---- fused tail: 1 thread per batch, f32 3x3 Jacobi eigensolve ----
    if (tid < BPB) {
        const int b = blockBase + tid;
        if (b < B) {
            float m[8];
#pragma unroll
            for (int k = 0; k < 8; ++k) m[k] = sA[tid][k];

            float A[3][3], V[3][3];
            A[0][0] = m[0] + 1e-05f;
            A[0][1] = m[1]; A[1][0] = m[1];
            A[0][2] = m[2]; A[2][0] = m[2];
            A[1][1] = m[3] + 2e-05f;
            A[1][2] = m[4]; A[2][1] = m[4];
            // trace identity: sum of squared unit norms = 128
            A[2][2] = (128.0f - m[0] - m[3]) + 3e-05f;
#pragma unroll
            for (int i = 0; i < 3; ++i)
#pragma unroll
                for (int j = 0; j < 3; ++j) V[i][j] = (i == j) ? 1.0f : 0.0f;

#pragma unroll
            for (int sweep = 0; sweep < 4; ++sweep) {   // 12 rotations
                jrot<0, 1, 2>(A, V);
                jrot<0, 2, 1>(A, V);
                jrot<1, 2, 0>(A, V);
            }

            float e0 = A[0][0], e1 = A[1][1], e2 = A[2][2];
            float c0x = V[0][0], c0y = V[1][0], c0z = V[2][0];
            float c1x = V[0][1], c1y = V[1][1], c1z = V[2][1];
            float c2x = V[0][2], c2y = V[1][2], c2z = V[2][2];

#define CSWAP(ea, eb, ax, ay, az, bx, by, bz)                         \
            if (ea > eb) {                                            \
                float t_;                                             \
                t_ = ea; ea = eb; eb = t_;                            \
                t_ = ax; ax = bx; bx = t_;                            \
                t_ = ay; ay = by; by = t_;                            \
                t_ = az; az = bz; bz = t_;                            \
            }
            CSWAP(e0, e1, c0x, c0y, c0z, c1x, c1y, c1z)
            CSWAP(e1, e2, c1x, c1y, c1z, c2x, c2y, c2z)
            CSWAP(e0, e1, c0x, c0y, c0z, c1x, c1y, c1z)
#undef CSWAP

            float s0 = m[5], s1 = m[6], s2 = m[7];
            float d1 = s0 * c0x + s1 * c0y + s2 * c0z;
            float f1 = (d1 < 0.0f) ? -1.0f : 1.0f;
            c0x *= f1; c0y *= f1; c0z *= f1;
            float d2 = s0 * c1x + s1 * c1y + s2 * c1z;
            float f2 = (d2 < 0.0f) ? -1.0f : 1.0f;
            c1x *= f2; c1y *= f2; c1z *= f2;

            float v3x = c0y * c1z - c0z * c1y;
            float v3y = c0z * c1x - c0x * c1z;
            float v3z = c0x * c1y - c0y * c1x;

            // stage frame in LDS for coalesced store
            sA[tid][0] = c0x; sA[tid][1] = c1x; sA[tid][2] = v3x;
            sA[tid][3] = c0y; sA[tid][4] = c1y; sA[tid][5] = v3y;
            sA[tid][6] = c0z; sA[tid][7] = c1z; sA[tid][8] = v3z;
        }
    }

    __syncthreads();

    // coalesced epilogue: 288 floats = 72 dwordx4
    if (blockBase + BPB <= B) {
        if (tid < 72) {
            const float4* s4 = reinterpret_cast<const float4*>(&sA[0][0]);
            float4* o4 = reinterpret_cast<float4*>(out + (size_t)blockBase * 9);
            o4[tid] = s4[tid];
        }
    } else if (tid < BPB) {                 // ragged last block fallback
        const int b = blockBase + tid;
        if (b < B) {
            float* o = out + (size_t)b * 9;
#pragma unroll
            for (int k = 0; k < 9; ++k) o[k] = sA[tid][k];
        }
    }
}

extern "C" void kernel_launch(void* const* d_in, const int* in_sizes, int n_in,
                              void* d_out, int out_size, void* d_ws, size_t ws_size,
                              hipStream_t stream) {
    const float* vf = (const float*)d_in[0];
    float* out = (float*)d_out;
    const int B = in_sizes[0] / 384;   // 128 vectors * 3 components
    const int grid = (B + BPB - 1) / BPB;
    vn_fused<<<dim3(grid), dim3(BLOCK), 0, stream>>>(vf, out, B);
}

// Round 9
// 24.608 us; speedup vs baseline: 1.0110x; 1.0110x over previous
//
#include <hip/hip_runtime.h>
#include <math.h>
#include <stdint.h>

// ---------------------------------------------------------------------------
// VNFrameEstimator, fully-f32 fused kernel, software-pipelined (R9):
//  - BPB=64 batches/block (1024 blocks): halves per-byte block ramp/drain.
//  - 16 lanes/batch; per-lane 6x float4 (96B) loads, double-buffered q0/q1:
//    batch t+1's loads issue before batch t's compute -> no steady-state stall.
//  - normalize with raw v_rsq_f32 on fmaxf-guarded n2; 8 moments (zz via
//    trace identity); 16-lane DPP row_ror rotate-reduce.
//  - tail: full wave (64 threads = 64 batches) f32 3x3 Jacobi, 4 sweeps,
//    sort, sign-fix, cross; frames staged in LDS; coalesced 144x dwordx4.
// ---------------------------------------------------------------------------

#define BLOCK 256
#define BPB   64
#define NIT   4    // batches per 16-lane group

// f32 rotate within the 16-lane DPP row (pure VALU). CTRL: ROW_ROR:N = 0x120|N.
template <int CTRL>
__device__ __forceinline__ float ror16_f32(float v) {
    union { float f; int i; } u, r;
    u.f = v;
    r.i = __builtin_amdgcn_mov_dpp(u.i, CTRL, 0xF, 0xF, true);
    return r.f;
}

// f32 1/sqrt, ~1 ulp (HW seed + 1 NR)
__device__ __forceinline__ float frsqrt(float x) {
    float r = __builtin_amdgcn_rsqf(x);
    return r * fmaf(-0.5f * x, r * r, 1.5f);
}
// f32 1/x, ~1 ulp (HW seed + 1 NR)
__device__ __forceinline__ float frcp(float x) {
    float r = __builtin_amdgcn_rcpf(x);
    return r * fmaf(-x, r, 2.0f);
}

// One f32 Jacobi rotation zeroing A[P][Q]; R is the remaining index.
template <int P, int Q, int R>
__device__ __forceinline__ void jrot(float (&A)[3][3], float (&V)[3][3]) {
    float apq = A[P][Q];
    if (fabsf(apq) > 1e-12f) {
        float theta = (A[Q][Q] - A[P][P]) * 0.5f * frcp(apq);
        float q = fmaf(theta, theta, 1.0f);
        float sq = q * frsqrt(q);                  // sqrt(theta^2+1)
        float t = frcp(fabsf(theta) + sq);
        if (theta < 0.0f) t = -t;
        float c = frsqrt(fmaf(t, t, 1.0f));
        float s = t * c;
        float apq_t = t * apq;
        A[P][P] = A[P][P] - apq_t;
        A[Q][Q] = A[Q][Q] + apq_t;
        A[P][Q] = 0.0f;
        A[Q][P] = 0.0f;
        float apr = A[P][R], aqr = A[Q][R];
        A[P][R] = fmaf(c, apr, -s * aqr); A[R][P] = A[P][R];
        A[Q][R] = fmaf(s, apr,  c * aqr); A[R][Q] = A[Q][R];
#pragma unroll
        for (int i = 0; i < 3; ++i) {
            float vip = V[i][P], viq = V[i][Q];
            V[i][P] = fmaf(c, vip, -s * viq);
            V[i][Q] = fmaf(s, vip,  c * viq);
        }
    }
}

// accumulate 8 vectors (24 floats) into 8 f32 moments
// m: [0]=xx [1]=xy [2]=xz [3]=yy [4]=yz [5]=sx [6]=sy [7]=sz   (zz via trace)
__device__ __forceinline__ void accum8(const float4 (&q)[6], float (&m)[8]) {
    float f[24];
#pragma unroll
    for (int i = 0; i < 6; ++i) {
        f[4 * i + 0] = q[i].x; f[4 * i + 1] = q[i].y;
        f[4 * i + 2] = q[i].z; f[4 * i + 3] = q[i].w;
    }
#pragma unroll
    for (int k = 0; k < 8; ++k) {
        float fx = f[3 * k + 0];
        float fy = f[3 * k + 1];
        float fz = f[3 * k + 2];
        float n2 = fmaf(fx, fx, fmaf(fy, fy, fz * fz));
        // rsq(max(n2,1e-24)) == reference 1e-12 norm clamp exactly
        float inv = __builtin_amdgcn_rsqf(fmaxf(n2, 1e-24f));
        float x = fx * inv;
        float y = fy * inv;
        float z = fz * inv;
        m[0] = fmaf(x, x, m[0]);
        m[1] = fmaf(x, y, m[1]);
        m[2] = fmaf(x, z, m[2]);
        m[3] = fmaf(y, y, m[3]);
        m[4] = fmaf(y, z, m[4]);
        m[5] += x; m[6] += y; m[7] += z;
    }
}

__device__ __forceinline__ void reduce16(float (&m)[8]) {
#pragma unroll
    for (int k = 0; k < 8; ++k) m[k] += ror16_f32<0x121>(m[k]);
#pragma unroll
    for (int k = 0; k < 8; ++k) m[k] += ror16_f32<0x122>(m[k]);
#pragma unroll
    for (int k = 0; k < 8; ++k) m[k] += ror16_f32<0x124>(m[k]);
#pragma unroll
    for (int k = 0; k < 8; ++k) m[k] += ror16_f32<0x128>(m[k]);
}

__global__ __launch_bounds__(BLOCK) void vn_fused(
    const float* __restrict__ vf, float* __restrict__ out, int B) {
    __shared__ __align__(16) float sA[BPB][9];   // moments, then frames

    const int tid  = threadIdx.x;
    const int wave = tid >> 6;
    const int lane = tid & 63;
    const int g    = lane >> 4;   // group within wave
    const int sub  = lane & 15;   // lane within 16-group

    const int blockBase = blockIdx.x * BPB;
    const int slot0 = wave * (4 * NIT) + g;       // batch slot at it=0

    auto loadq = [&](int b, float4 (&q)[6]) {
        const float4* p =
            reinterpret_cast<const float4*>(vf + (size_t)b * 384 + sub * 24);
#pragma unroll
        for (int i = 0; i < 6; ++i) q[i] = p[i];
    };

    float4 q0[6], q1[6];
    {
        const int b0 = blockBase + slot0;
        if (b0 < B) loadq(b0, q0);
    }

#pragma unroll
    for (int it = 0; it < NIT; ++it) {
        float4 (&qc)[6] = (it & 1) ? q1 : q0;   // current (static after unroll)
        float4 (&qn)[6] = (it & 1) ? q0 : q1;   // prefetch target
        const int slot = slot0 + it * 4;
        const int b = blockBase + slot;
        if (it + 1 < NIT) {
            const int bn = b + 4;
            if (bn < B) loadq(bn, qn);          // issue next batch's loads first
        }
        if (b < B) {
            float m[8];
#pragma unroll
            for (int k = 0; k < 8; ++k) m[k] = 0.0f;
            accum8(qc, m);
            reduce16(m);
            if (sub == 0) {
#pragma unroll
                for (int k = 0; k < 8; ++k) sA[slot][k] = m[k];
            }
        }
    }

    __syncthreads();

    // ---- tail: one full wave, 1 thread/batch f32 3x3 Jacobi ----
    if (tid < BPB) {
        const int b = blockBase + tid;
        if (b < B) {
            float m[8];
#pragma unroll
            for (int k = 0; k < 8; ++k) m[k] = sA[tid][k];

            float A[3][3], V[3][3];
            A[0][0] = m[0] + 1e-05f;
            A[0][1] = m[1]; A[1][0] = m[1];
            A[0][2] = m[2]; A[2][0] = m[2];
            A[1][1] = m[3] + 2e-05f;
            A[1][2] = m[4]; A[2][1] = m[4];
            // trace identity: sum of squared unit norms = 128
            A[2][2] = (128.0f - m[0] - m[3]) + 3e-05f;
#pragma unroll
            for (int i = 0; i < 3; ++i)
#pragma unroll
                for (int j = 0; j < 3; ++j) V[i][j] = (i == j) ? 1.0f : 0.0f;

#pragma unroll
            for (int sweep = 0; sweep < 4; ++sweep) {   // 12 rotations
                jrot<0, 1, 2>(A, V);
                jrot<0, 2, 1>(A, V);
                jrot<1, 2, 0>(A, V);
            }

            float e0 = A[0][0], e1 = A[1][1], e2 = A[2][2];
            float c0x = V[0][0], c0y = V[1][0], c0z = V[2][0];
            float c1x = V[0][1], c1y = V[1][1], c1z = V[2][1];
            float c2x = V[0][2], c2y = V[1][2], c2z = V[2][2];

#define CSWAP(ea, eb, ax, ay, az, bx, by, bz)                         \
            if (ea > eb) {                                            \
                float t_;                                             \
                t_ = ea; ea = eb; eb = t_;                            \
                t_ = ax; ax = bx; bx = t_;                            \
                t_ = ay; ay = by; by = t_;                            \
                t_ = az; az = bz; bz = t_;                            \
            }
            CSWAP(e0, e1, c0x, c0y, c0z, c1x, c1y, c1z)
            CSWAP(e1, e2, c1x, c1y, c1z, c2x, c2y, c2z)
            CSWAP(e0, e1, c0x, c0y, c0z, c1x, c1y, c1z)
#undef CSWAP

            float s0 = m[5], s1 = m[6], s2 = m[7];
            float d1 = s0 * c0x + s1 * c0y + s2 * c0z;
            float f1 = (d1 < 0.0f) ? -1.0f : 1.0f;
            c0x *= f1; c0y *= f1; c0z *= f1;
            float d2 = s0 * c1x + s1 * c1y + s2 * c1z;
            float f2 = (d2 < 0.0f) ? -1.0f : 1.0f;
            c1x *= f2; c1y *= f2; c1z *= f2;

            float v3x = c0y * c1z - c0z * c1y;
            float v3y = c0z * c1x - c0x * c1z;
            float v3z = c0x * c1y - c0y * c1x;

            // stage frame in LDS for coalesced store
            sA[tid][0] = c0x; sA[tid][1] = c1x; sA[tid][2] = v3x;
            sA[tid][3] = c0y; sA[tid][4] = c1y; sA[tid][5] = v3y;
            sA[tid][6] = c0z; sA[tid][7] = c1z; sA[tid][8] = v3z;
        }
    }

    __syncthreads();

    // coalesced epilogue: BPB*9 = 576 floats = 144 dwordx4
    if (blockBase + BPB <= B) {
        if (tid < (BPB * 9) / 4) {
            const float4* s4 = reinterpret_cast<const float4*>(&sA[0][0]);
            float4* o4 = reinterpret_cast<float4*>(out + (size_t)blockBase * 9);
            o4[tid] = s4[tid];
        }
    } else if (tid < BPB) {                 // ragged last block fallback
        const int b = blockBase + tid;
        if (b < B) {
            float* o = out + (size_t)b * 9;
#pragma unroll
            for (int k = 0; k < 9; ++k) o[k] = sA[tid][k];
        }
    }
}

extern "C" void kernel_launch(void* const* d_in, const int* in_sizes, int n_in,
                              void* d_out, int out_size, void* d_ws, size_t ws_size,
                              hipStream_t stream) {
    const float* vf = (const float*)d_in[0];
    float* out = (float*)d_out;
    const int B = in_sizes[0] / 384;   // 128 vectors * 3 components
    const int grid = (B + BPB - 1) / BPB;
    vn_fused<<<dim3(grid), dim3(BLOCK), 0, stream>>>(vf, out, B);
}